// Round 3
// baseline (672.470 us; speedup 1.0000x reference)
//
#include <hip/hip_runtime.h>
#include <hip/hip_bf16.h>

#define Bdim 64
#define Tdim 96
#define Pdim 256
#define Hdim 128
#define Gdim 512   // 4*H
#define Odim 24
#define BH   32    // batches per block (one stream per block this round)

typedef _Float16 f16x8 __attribute__((ext_vector_type(8)));
typedef float    f32x16 __attribute__((ext_vector_type(16)));
typedef float    f32x2  __attribute__((ext_vector_type(2)));

union H8 { uint4 u4; unsigned short s[8]; _Float16 h[8]; f16x8 v; };
union HS { _Float16 h; unsigned short s; };

__device__ __forceinline__ float exp2_fast(float x) {
#if __has_builtin(__builtin_amdgcn_exp2f)
    return __builtin_amdgcn_exp2f(x);
#else
    return __expf(x * 0.6931471805599453f);
#endif
}

// THIS ROUND: occupancy fix. R2 counters: Occupancy 45% (= exactly 1 block/CU,
// grid 256), VALUBusy 55%, MfmaUtil 32%, HBM 2.8% -> latency-bound with no
// co-resident work to fill barrier drains. Split the two 32-batch streams into
// two BLOCKS: grid 512 (p = bid&255, s = bid>>8 -> stream-pair of a point lands
// on the same XCD for shared W L2 hits). Each block: 16 waves, one stream,
// 16 KiB LDS, one barrier/step; cross-block TLP replaces intra-block ILP.
// __launch_bounds__(1024,8) caps regs at 64/wave so 2 blocks/CU fit (persistent:
// afr[0..7]=32 + wb9(packed 9th frag)=1 + acc=16 + cre=4 ~= 53).
//
// h storage: row b = 256 B = 16 chunks of 16 B, chunk c stored at position
// c ^ (b & 15) (XOR swizzle). Gemm read of chunk c = 2ks+hi by lane b=l31 is ONE
// aligned ds_read_b128 at byte offset 256*l31 + 16*(c^(l31&15)) -> balanced banks.
//
// Math (verified R2, absmax 9.8e-4): log2e-prescaled weights (2log2e for g),
// gx fused as 9th MFMA K-step, scaled-domain cell state (cr = 2*log2e*c),
// paired-rcp epilogue (6 trans per (b,k)).
__global__ __launch_bounds__(1024, 8)
void lstm_fused(const float* __restrict__ x,
                const float* __restrict__ W_ih,
                const float* __restrict__ W_hh,
                const float* __restrict__ b_ih,
                const float* __restrict__ b_hh,
                const float* __restrict__ W_fc,
                const float* __restrict__ b_fc,
                float* __restrict__ out)
{
    __shared__ unsigned short hb[2][BH * Hdim];  // h, double-buffered, swizzled

    const int bid = blockIdx.x;
    const int p   = bid & 255;   // point
    const int s   = bid >> 8;    // stream (batch half): 0 or 1
    const int tid = threadIdx.x;
    const int w   = tid >> 6;    // wave 0..15
    const int l31 = tid & 31;
    const int hi  = (tid >> 5) & 1;

    const float L1 = 1.4426950408889634f;  // log2(e)
    const float L2 = 2.0f * L1;

    for (int i = tid; i < 2 * BH * Hdim; i += 1024) ((unsigned short*)hb)[i] = 0;

    // ---- preload A fragments (time-invariant): W_hh rows; 9th row packed ----
    f16x8 afr[8];
    unsigned int wb9;
    {
        const int rp   = w * 32 + l31;                // r'
        const int orow = ((rp & 3) << 7) | (rp >> 2); // gate*128 + k
        const float sc = ((rp & 3) == 2) ? L2 : L1;   // g gate: 2*log2e
        const float* rowp = W_hh + (size_t)p * Gdim * Hdim + (size_t)orow * Hdim;
        #pragma unroll
        for (int ks = 0; ks < 8; ++ks) {
            int k0 = ks * 16 + hi * 8;
            float4 va = *(const float4*)(rowp + k0);
            float4 vb = *(const float4*)(rowp + k0 + 4);
            H8 u;
            u.h[0] = (_Float16)(sc * va.x); u.h[1] = (_Float16)(sc * va.y);
            u.h[2] = (_Float16)(sc * va.z); u.h[3] = (_Float16)(sc * va.w);
            u.h[4] = (_Float16)(sc * vb.x); u.h[5] = (_Float16)(sc * vb.y);
            u.h[6] = (_Float16)(sc * vb.z); u.h[7] = (_Float16)(sc * vb.w);
            afr[ks] = u.v;
        }
        HS t0; t0.h = (_Float16)(sc * W_ih[(size_t)p * Gdim + orow]);
        HS t1; t1.h = (_Float16)(sc * (b_ih[(size_t)p * Gdim + orow] +
                                       b_hh[(size_t)p * Gdim + orow]));
        wb9 = (hi == 0) ? ((unsigned)t0.s | ((unsigned)t1.s << 16)) : 0u;
    }

    // swizzled ds_read_b128: row l31, chunk c = 2ks+hi
    auto ldh = [&](const unsigned short* rb, int ks) -> H8 {
        H8 r;
        int c   = ks * 2 + hi;
        int off = (l31 << 8) + ((c ^ (l31 & 15)) << 4);   // bytes
        r.u4 = *(const uint4*)((const char*)rb + off);
        return r;
    };

    // epilogue for q-pair (q=2j, 2j+1): acc -> new c (in cr), h -> wb (swizzled)
    auto ep_pair = [&](const f32x16& a, int j, f32x2* cr, unsigned short* wb) {
        f32x2 yi = {a[8 * j + 0], a[8 * j + 4]};
        f32x2 yf = {a[8 * j + 1], a[8 * j + 5]};
        f32x2 yg = {a[8 * j + 2], a[8 * j + 6]};   // prescaled by 2*log2e
        f32x2 yo = {a[8 * j + 3], a[8 * j + 7]};
        f32x2 Ef = {exp2_fast(-yf.x), exp2_fast(-yf.y)};
        f32x2 Ei = {exp2_fast(-yi.x), exp2_fast(-yi.y)};
        f32x2 Eg = {exp2_fast(yg.x),  exp2_fast(yg.y)};
        f32x2 t1 = Ef + 1.0f;
        f32x2 t2 = Ei + 1.0f;
        f32x2 t3 = Eg + 1.0f;
        f32x2 t4 = Eg - 1.0f;
        f32x2 den = (t1 * t2) * t3;
        f32x2 num = (cr[j] * t2) * t3 + (L2 * t4) * t1;
        float D = den.x * den.y;
        float r = __builtin_amdgcn_rcpf(D);
        f32x2 inv = {r * den.y, r * den.x};
        f32x2 cn  = num * inv;
        cn.x = __builtin_amdgcn_fmed3f(cn.x, -30.0f, 30.0f);
        cn.y = __builtin_amdgcn_fmed3f(cn.y, -30.0f, 30.0f);
        cr[j] = cn;
        f32x2 Eo = {exp2_fast(-yo.x), exp2_fast(-yo.y)};
        f32x2 Ec = {exp2_fast(cn.x),  exp2_fast(cn.y)};
        f32x2 d2 = (Eo + 1.0f) * (Ec + 1.0f);
        float D2 = d2.x * d2.y;
        float r2 = __builtin_amdgcn_rcpf(D2);
        f32x2 j2 = {r2 * d2.y, r2 * d2.x};
        f32x2 hv = (Ec - 1.0f) * j2;
        HS ha; ha.h = (_Float16)hv.x;
        HS hc; hc.h = (_Float16)hv.y;
        // k = w*8 + 4j + hi (+2); chunk = w -> swizzled pos = w ^ (l31&15)
        int base = (l31 << 7) + ((w ^ (l31 & 15)) << 3) + 4 * j + hi;
        wb[base]     = ha.s;   // q = 2j
        wb[base + 2] = hc.s;   // q = 2j+1
    };

    f32x2 cre[2] = {f32x2{0.f, 0.f}, f32x2{0.f, 0.f}};

    const float* xp = x + (size_t)((s * BH + l31) * Tdim) * Pdim + p;
    float xv = xp[0];

    __syncthreads();

    for (int t = 0; t < Tdim; ++t) {
        const int P  = t & 1;
        const unsigned short* rb = hb[P];
        unsigned short*       wb = hb[P ^ 1];
        const int tn = (t + 1 < Tdim) ? (t + 1) : t;
        float xn = xp[(size_t)tn * Pdim];   // prefetch x(t+1)

        // ---- gemm: gates = [W_hh | gx-row] * [h ; (x,1)] ----
        f32x16 acc;
        {
            H8 f0 = ldh(rb, 0), f1 = ldh(rb, 1);
            f32x16 z;
            #pragma unroll
            for (int j = 0; j < 16; ++j) z[j] = 0.f;
            acc = __builtin_amdgcn_mfma_f32_32x32x16_f16(afr[0], f0.v, z, 0, 0, 0);
            H8 f2 = ldh(rb, 2), f3 = ldh(rb, 3);
            acc = __builtin_amdgcn_mfma_f32_32x32x16_f16(afr[1], f1.v, acc, 0, 0, 0);
            acc = __builtin_amdgcn_mfma_f32_32x32x16_f16(afr[2], f2.v, acc, 0, 0, 0);
            H8 f4 = ldh(rb, 4), f5 = ldh(rb, 5);
            acc = __builtin_amdgcn_mfma_f32_32x32x16_f16(afr[3], f3.v, acc, 0, 0, 0);
            acc = __builtin_amdgcn_mfma_f32_32x32x16_f16(afr[4], f4.v, acc, 0, 0, 0);
            H8 f6 = ldh(rb, 6), f7 = ldh(rb, 7);
            acc = __builtin_amdgcn_mfma_f32_32x32x16_f16(afr[5], f5.v, acc, 0, 0, 0);
            acc = __builtin_amdgcn_mfma_f32_32x32x16_f16(afr[6], f6.v, acc, 0, 0, 0);
            acc = __builtin_amdgcn_mfma_f32_32x32x16_f16(afr[7], f7.v, acc, 0, 0, 0);
            // 9th K-step: A = packed (W_ih, b) row, B = packed (x, 1)
            H8 a9; a9.u4.x = wb9; a9.u4.y = 0; a9.u4.z = 0; a9.u4.w = 0;
            HS bx; bx.h = (_Float16)xv;
            H8 bg; bg.u4.x = (hi == 0) ? ((unsigned)bx.s | (0x3C00u << 16)) : 0u;
            bg.u4.y = 0; bg.u4.z = 0; bg.u4.w = 0;
            acc = __builtin_amdgcn_mfma_f32_32x32x16_f16(a9.v, bg.v, acc, 0, 0, 0);
        }

        // ---- epilogue: acc -> (c, h), h written swizzled to wb ----
        ep_pair(acc, 0, cre, wb);
        ep_pair(acc, 1, cre, wb);

        __syncthreads();
        xv = xn;
    }
    // final h (t=95 writes buffer 0): hb[0], swizzled

    // ---- FC: out[b][o][p] = sum_k W_fc[p][o][k]*h[b][k] + b_fc[p][o] ----
    const float* wfc = W_fc + (size_t)p * Odim * Hdim;
    const float* bfc = b_fc + (size_t)p * Odim;
    for (int i = tid; i < BH * Odim; i += 1024) {
        int o  = i % Odim;
        int bl = i / Odim;           // local batch 0..31
        int b  = s * BH + bl;        // global batch
        const unsigned short* hr = hb[0] + (bl << 7);
        float sum = bfc[o];
        const float* wr = wfc + o * Hdim;
        #pragma unroll 8
        for (int k2 = 0; k2 < Hdim; ++k2) {
            int idx = (((k2 >> 3) ^ (bl & 15)) << 3) + (k2 & 7);   // unswizzle
            HS s2; s2.s = hr[idx];
            sum = __builtin_fmaf(wr[k2], (float)s2.h, sum);
        }
        out[(size_t)b * Odim * Pdim + (size_t)o * Pdim + p] = sum;
    }
}

extern "C" void kernel_launch(void* const* d_in, const int* in_sizes, int n_in,
                              void* d_out, int out_size, void* d_ws, size_t ws_size,
                              hipStream_t stream) {
    const float* x    = (const float*)d_in[0];
    const float* W_ih = (const float*)d_in[1];
    const float* W_hh = (const float*)d_in[2];
    const float* b_ih = (const float*)d_in[3];
    const float* b_hh = (const float*)d_in[4];
    const float* W_fc = (const float*)d_in[5];
    const float* b_fc = (const float*)d_in[6];
    float* out = (float*)d_out;

    lstm_fused<<<dim3(2 * Pdim), dim3(1024), 0, stream>>>(x, W_ih, W_hh, b_ih, b_hh, W_fc, b_fc, out);
}

// Round 4
// 433.529 us; speedup vs baseline: 1.5512x; 1.5512x over previous
//
#include <hip/hip_runtime.h>
#include <hip/hip_bf16.h>

#define Bdim 64
#define Tdim 96
#define Pdim 256
#define Hdim 128
#define Gdim 512   // 4*H
#define Odim 24
#define BH   32    // batches per block (one stream per block)

typedef _Float16 f16x8 __attribute__((ext_vector_type(8)));
typedef float    f32x16 __attribute__((ext_vector_type(16)));
typedef float    f32x2  __attribute__((ext_vector_type(2)));

union H8 { uint4 u4; unsigned short s[8]; _Float16 h[8]; f16x8 v; };
union HS { _Float16 h; unsigned short s; };

__device__ __forceinline__ float exp2_fast(float x) {
#if __has_builtin(__builtin_amdgcn_exp2f)
    return __builtin_amdgcn_exp2f(x);
#else
    return __expf(x * 0.6931471805599453f);
#endif
}

// R4: 16 waves/CU is a hard budget (R3 post-mortem: 8 waves/SIMD -> 64-VGPR cap
// -> afr/acc spill -> 875 MB scratch traffic, 2x regression). Reorganize those
// 16 waves: two 8-wave blocks (one 32-batch stream each, grid 512), each wave
// owns TWO 32-row A-blocks (rows of wave w: [32w..) and [32(w+8)..)):
//  * B-reuse: 8 ds_read_b128 of h feed 18 MFMAs (R2: 16 reads) -> LDS traffic
//    and bank conflicts halve on the dominant stream.
//  * barrier drains only 8 waves; the other block fills the CU (m114).
//  * two interleaved independent MFMA chains -> dep distance 2.
// VGPR: afr 64 + acc 32 + cre 8 + wb9 2 + temps ~= 125 < 128 cap at
// __launch_bounds__(512,4). Gate counters: VGPR<=128, FETCH ~60 MB (no spill).
//
// h storage: row b = 256 B = 16 chunks of 16 B, chunk c at position c ^ (b&15)
// (XOR swizzle). Gemm read of chunk c = 2ks+hi by lane b=l31 is ONE aligned
// ds_read_b128 at byte offset 256*l31 + 16*(c^(l31&15)) -> balanced banks.
//
// Math (verified R2/R3, absmax 9.8e-4): log2e-prescaled weights (2log2e for g),
// gx fused as 9th MFMA K-step, scaled-domain cell state, paired-rcp epilogue.
__global__ __launch_bounds__(512, 4)
void lstm_fused(const float* __restrict__ x,
                const float* __restrict__ W_ih,
                const float* __restrict__ W_hh,
                const float* __restrict__ b_ih,
                const float* __restrict__ b_hh,
                const float* __restrict__ W_fc,
                const float* __restrict__ b_fc,
                float* __restrict__ out)
{
    __shared__ unsigned short hb[2][BH * Hdim];  // h, double-buffered, swizzled

    const int bid = blockIdx.x;
    const int p   = bid & 255;   // point
    const int s   = bid >> 8;    // stream (batch half): 0 or 1
    const int tid = threadIdx.x;
    const int w   = tid >> 6;    // wave 0..7
    const int l31 = tid & 31;
    const int hi  = (tid >> 5) & 1;

    const float L1 = 1.4426950408889634f;  // log2(e)
    const float L2 = 2.0f * L1;

    for (int i = tid; i < 2 * BH * Hdim; i += 512) ((unsigned short*)hb)[i] = 0;

    // ---- preload A fragments for both row-blocks (time-invariant) ----
    f16x8 afrA[8], afrB[8];
    unsigned int wb9A, wb9B;
    auto preload = [&](int we, f16x8* afr) -> unsigned int {
        const int rp   = we * 32 + l31;               // r'
        const int orow = ((rp & 3) << 7) | (rp >> 2); // gate*128 + k
        const float sc = ((rp & 3) == 2) ? L2 : L1;   // g gate: 2*log2e
        const float* rowp = W_hh + (size_t)p * Gdim * Hdim + (size_t)orow * Hdim;
        #pragma unroll
        for (int ks = 0; ks < 8; ++ks) {
            int k0 = ks * 16 + hi * 8;
            float4 va = *(const float4*)(rowp + k0);
            float4 vb = *(const float4*)(rowp + k0 + 4);
            H8 u;
            u.h[0] = (_Float16)(sc * va.x); u.h[1] = (_Float16)(sc * va.y);
            u.h[2] = (_Float16)(sc * va.z); u.h[3] = (_Float16)(sc * va.w);
            u.h[4] = (_Float16)(sc * vb.x); u.h[5] = (_Float16)(sc * vb.y);
            u.h[6] = (_Float16)(sc * vb.z); u.h[7] = (_Float16)(sc * vb.w);
            afr[ks] = u.v;
        }
        HS t0; t0.h = (_Float16)(sc * W_ih[(size_t)p * Gdim + orow]);
        HS t1; t1.h = (_Float16)(sc * (b_ih[(size_t)p * Gdim + orow] +
                                       b_hh[(size_t)p * Gdim + orow]));
        return (hi == 0) ? ((unsigned)t0.s | ((unsigned)t1.s << 16)) : 0u;
    };
    wb9A = preload(w,     afrA);
    wb9B = preload(w + 8, afrB);

    // swizzled ds_read_b128: row l31, chunk c = 2ks+hi
    auto ldh = [&](const unsigned short* rb, int ks) -> H8 {
        H8 r;
        int c   = ks * 2 + hi;
        int off = (l31 << 8) + ((c ^ (l31 & 15)) << 4);   // bytes
        r.u4 = *(const uint4*)((const char*)rb + off);
        return r;
    };

    // epilogue for q-pair (q=2j, 2j+1): acc -> new c (in cr), h -> wb (swizzled)
    // we = row-block wave index (w or w+8) -> h chunk index
    auto ep_pair = [&](const f32x16& a, int j, f32x2* cr, unsigned short* wb,
                       int we) {
        f32x2 yi = {a[8 * j + 0], a[8 * j + 4]};
        f32x2 yf = {a[8 * j + 1], a[8 * j + 5]};
        f32x2 yg = {a[8 * j + 2], a[8 * j + 6]};   // prescaled by 2*log2e
        f32x2 yo = {a[8 * j + 3], a[8 * j + 7]};
        f32x2 Ef = {exp2_fast(-yf.x), exp2_fast(-yf.y)};
        f32x2 Ei = {exp2_fast(-yi.x), exp2_fast(-yi.y)};
        f32x2 Eg = {exp2_fast(yg.x),  exp2_fast(yg.y)};
        f32x2 t1 = Ef + 1.0f;
        f32x2 t2 = Ei + 1.0f;
        f32x2 t3 = Eg + 1.0f;
        f32x2 t4 = Eg - 1.0f;
        f32x2 den = (t1 * t2) * t3;
        f32x2 num = (cr[j] * t2) * t3 + (L2 * t4) * t1;
        float D = den.x * den.y;
        float r = __builtin_amdgcn_rcpf(D);
        f32x2 inv = {r * den.y, r * den.x};
        f32x2 cn  = num * inv;
        cn.x = __builtin_amdgcn_fmed3f(cn.x, -30.0f, 30.0f);
        cn.y = __builtin_amdgcn_fmed3f(cn.y, -30.0f, 30.0f);
        cr[j] = cn;
        f32x2 Eo = {exp2_fast(-yo.x), exp2_fast(-yo.y)};
        f32x2 Ec = {exp2_fast(cn.x),  exp2_fast(cn.y)};
        f32x2 d2 = (Eo + 1.0f) * (Ec + 1.0f);
        float D2 = d2.x * d2.y;
        float r2 = __builtin_amdgcn_rcpf(D2);
        f32x2 j2 = {r2 * d2.y, r2 * d2.x};
        f32x2 hv = (Ec - 1.0f) * j2;
        HS ha; ha.h = (_Float16)hv.x;
        HS hc; hc.h = (_Float16)hv.y;
        // k = we*8 + 4j + hi (+2); chunk = we -> swizzled pos = we ^ (l31&15)
        int base = (l31 << 7) + ((we ^ (l31 & 15)) << 3) + 4 * j + hi;
        wb[base]     = ha.s;   // q = 2j
        wb[base + 2] = hc.s;   // q = 2j+1
    };

    f32x2 creA[2] = {f32x2{0.f, 0.f}, f32x2{0.f, 0.f}};
    f32x2 creB[2] = {f32x2{0.f, 0.f}, f32x2{0.f, 0.f}};

    const float* xp = x + (size_t)((s * BH + l31) * Tdim) * Pdim + p;
    float xv = xp[0];

    __syncthreads();

    for (int t = 0; t < Tdim; ++t) {
        const int P  = t & 1;
        const unsigned short* rb = hb[P];
        unsigned short*       wb = hb[P ^ 1];
        const int tn = (t + 1 < Tdim) ? (t + 1) : t;
        float xn = xp[(size_t)tn * Pdim];   // prefetch x(t+1)

        // ---- gemm: two interleaved 9-MFMA chains sharing the same h frags ----
        f32x16 accA, accB;
        {
            f32x16 z;
            #pragma unroll
            for (int j = 0; j < 16; ++j) z[j] = 0.f;
            H8 f0 = ldh(rb, 0), f1 = ldh(rb, 1);
            accA = __builtin_amdgcn_mfma_f32_32x32x16_f16(afrA[0], f0.v, z, 0, 0, 0);
            accB = __builtin_amdgcn_mfma_f32_32x32x16_f16(afrB[0], f0.v, z, 0, 0, 0);
            H8 f2 = ldh(rb, 2), f3 = ldh(rb, 3);
            accA = __builtin_amdgcn_mfma_f32_32x32x16_f16(afrA[1], f1.v, accA, 0, 0, 0);
            accB = __builtin_amdgcn_mfma_f32_32x32x16_f16(afrB[1], f1.v, accB, 0, 0, 0);
            accA = __builtin_amdgcn_mfma_f32_32x32x16_f16(afrA[2], f2.v, accA, 0, 0, 0);
            accB = __builtin_amdgcn_mfma_f32_32x32x16_f16(afrB[2], f2.v, accB, 0, 0, 0);
            H8 f4 = ldh(rb, 4), f5 = ldh(rb, 5);
            accA = __builtin_amdgcn_mfma_f32_32x32x16_f16(afrA[3], f3.v, accA, 0, 0, 0);
            accB = __builtin_amdgcn_mfma_f32_32x32x16_f16(afrB[3], f3.v, accB, 0, 0, 0);
            accA = __builtin_amdgcn_mfma_f32_32x32x16_f16(afrA[4], f4.v, accA, 0, 0, 0);
            accB = __builtin_amdgcn_mfma_f32_32x32x16_f16(afrB[4], f4.v, accB, 0, 0, 0);
            H8 f6 = ldh(rb, 6), f7 = ldh(rb, 7);
            accA = __builtin_amdgcn_mfma_f32_32x32x16_f16(afrA[5], f5.v, accA, 0, 0, 0);
            accB = __builtin_amdgcn_mfma_f32_32x32x16_f16(afrB[5], f5.v, accB, 0, 0, 0);
            accA = __builtin_amdgcn_mfma_f32_32x32x16_f16(afrA[6], f6.v, accA, 0, 0, 0);
            accB = __builtin_amdgcn_mfma_f32_32x32x16_f16(afrB[6], f6.v, accB, 0, 0, 0);
            accA = __builtin_amdgcn_mfma_f32_32x32x16_f16(afrA[7], f7.v, accA, 0, 0, 0);
            accB = __builtin_amdgcn_mfma_f32_32x32x16_f16(afrB[7], f7.v, accB, 0, 0, 0);
            // 9th K-step: A = packed (W_ih, b) row, B = packed (x, 1)
            H8 a9A; a9A.u4.x = wb9A; a9A.u4.y = 0; a9A.u4.z = 0; a9A.u4.w = 0;
            H8 a9B; a9B.u4.x = wb9B; a9B.u4.y = 0; a9B.u4.z = 0; a9B.u4.w = 0;
            HS bx; bx.h = (_Float16)xv;
            H8 bg; bg.u4.x = (hi == 0) ? ((unsigned)bx.s | (0x3C00u << 16)) : 0u;
            bg.u4.y = 0; bg.u4.z = 0; bg.u4.w = 0;
            accA = __builtin_amdgcn_mfma_f32_32x32x16_f16(a9A.v, bg.v, accA, 0, 0, 0);
            accB = __builtin_amdgcn_mfma_f32_32x32x16_f16(a9B.v, bg.v, accB, 0, 0, 0);
        }

        // ---- epilogue: acc -> (c, h), h written swizzled to wb ----
        ep_pair(accA, 0, creA, wb, w);
        ep_pair(accA, 1, creA, wb, w);
        ep_pair(accB, 0, creB, wb, w + 8);
        ep_pair(accB, 1, creB, wb, w + 8);

        __syncthreads();
        xv = xn;
    }
    // final h (t=95 writes buffer 0): hb[0], swizzled

    // ---- FC: out[b][o][p] = sum_k W_fc[p][o][k]*h[b][k] + b_fc[p][o] ----
    const float* wfc = W_fc + (size_t)p * Odim * Hdim;
    const float* bfc = b_fc + (size_t)p * Odim;
    for (int i = tid; i < BH * Odim; i += 512) {
        int o  = i % Odim;
        int bl = i / Odim;           // local batch 0..31
        int b  = s * BH + bl;        // global batch
        const unsigned short* hr = hb[0] + (bl << 7);
        float sum = bfc[o];
        const float* wr = wfc + o * Hdim;
        #pragma unroll 8
        for (int k2 = 0; k2 < Hdim; ++k2) {
            int idx = (((k2 >> 3) ^ (bl & 15)) << 3) + (k2 & 7);   // unswizzle
            HS s2; s2.s = hr[idx];
            sum = __builtin_fmaf(wr[k2], (float)s2.h, sum);
        }
        out[(size_t)b * Odim * Pdim + (size_t)o * Pdim + p] = sum;
    }
}

extern "C" void kernel_launch(void* const* d_in, const int* in_sizes, int n_in,
                              void* d_out, int out_size, void* d_ws, size_t ws_size,
                              hipStream_t stream) {
    const float* x    = (const float*)d_in[0];
    const float* W_ih = (const float*)d_in[1];
    const float* W_hh = (const float*)d_in[2];
    const float* b_ih = (const float*)d_in[3];
    const float* b_hh = (const float*)d_in[4];
    const float* W_fc = (const float*)d_in[5];
    const float* b_fc = (const float*)d_in[6];
    float* out = (float*)d_out;

    lstm_fused<<<dim3(2 * Pdim), dim3(512), 0, stream>>>(x, W_ih, W_hh, b_ih, b_hh, W_fc, b_fc, out);
}

// Round 5
// 390.273 us; speedup vs baseline: 1.7231x; 1.1108x over previous
//
#include <hip/hip_runtime.h>
#include <hip/hip_bf16.h>

#define Bdim 64
#define Tdim 96
#define Pdim 256
#define Hdim 128
#define Gdim 512   // 4*H
#define Odim 24
#define BH   32    // batches per stream (two streams per block)

typedef _Float16 f16x8 __attribute__((ext_vector_type(8)));
typedef float    f32x16 __attribute__((ext_vector_type(16)));
typedef float    f32x2  __attribute__((ext_vector_type(2)));

union H8 { uint4 u4; unsigned short s[8]; _Float16 h[8]; f16x8 v; };
union HS { _Float16 h; unsigned short s; };

__device__ __forceinline__ float exp2_fast(float x) {
#if __has_builtin(__builtin_amdgcn_exp2f)
    return __builtin_amdgcn_exp2f(x);
#else
    return __expf(x * 0.6931471805599453f);
#endif
}

// R5: R2 structure (measured best, 330us rocprof) + packed h-writes.
// R2 counters: SQ_LDS_BANK_CONFLICT 1.887e7 (constant across variants ->
// structural) ~= 768 cy/CU/step ~= 9%. Bank math: the 8x ds_write_b16/wave of
// the epilogue land on only 8 banks (8-way, ~2.94x). Fix: rotate the 3 low bits
// of the k-index mapping (kl = ((u&1)<<2)|(u>>1), applied identically to A-row
// preload and epilogue decode) so each lane's 4 h outputs are CONTIGUOUS shorts
// -> 2 aligned ds_write_b64/wave/step at 4-way (~1.58x). Chunk invariant
// "position m holds k = chunk*8+m" preserved -> read path + FC unswizzle
// untouched. Also: gx-MFMA (afr[8], no LDS dep) issued FIRST in the chain.
//
// h storage: row b = 256 B = 16 chunks of 16 B, chunk c at position c ^ (b&15)
// (XOR swizzle). Gemm read of chunk c = 2ks+hi by lane b=l31 is ONE aligned
// ds_read_b128 at byte offset 256*l31 + 16*(c^(l31&15)) -> balanced banks.
//
// Math (verified R2-R4, absmax 9.77e-4): log2e-prescaled weights (2log2e for g),
// gx fused as 9th MFMA K-step, scaled-domain cell state, paired-rcp epilogue.
// Schedule: single barrier per step; gemm_s0; {gemm_s1 || ep_s0}; ep_s1.
__global__ __launch_bounds__(1024, 4)
void lstm_fused(const float* __restrict__ x,
                const float* __restrict__ W_ih,
                const float* __restrict__ W_hh,
                const float* __restrict__ b_ih,
                const float* __restrict__ b_hh,
                const float* __restrict__ W_fc,
                const float* __restrict__ b_fc,
                float* __restrict__ out)
{
    __shared__ alignas(16) unsigned short hb0[2][BH * Hdim];  // stream0 h, dbuf, swizzled
    __shared__ alignas(16) unsigned short hb1[2][BH * Hdim];  // stream1 h, dbuf, swizzled

    const int p   = blockIdx.x;
    const int tid = threadIdx.x;
    const int w   = tid >> 6;    // wave 0..15
    const int l31 = tid & 31;
    const int hi  = (tid >> 5) & 1;

    const float L1 = 1.4426950408889634f;  // log2(e)
    const float L2 = 2.0f * L1;

    for (int i = tid; i < 2 * BH * Hdim; i += 1024) ((unsigned short*)hb0)[i] = 0;
    for (int i = tid; i < 2 * BH * Hdim; i += 1024) ((unsigned short*)hb1)[i] = 0;

    // ---- preload shared A fragments (time-invariant): W_hh rows + gx row ----
    // Row-meaning remap: block-row r -> gate = r&3, k_local = rot(r>>2) where
    // rot(u) = ((u&1)<<2)|(u>>1). This makes the epilogue's per-lane k's
    // contiguous (k = w*8 + 4*hi + {0..3}) while keeping "chunk pos m = k
    // chunk*8+m" so the gemm-read/FC layout is unchanged.
    f16x8 afr[9];
    {
        const int rp   = w * 32 + l31;                 // block row id
        const int u    = l31 >> 2;                     // 3-bit within-chunk idx
        const int kl   = ((u & 1) << 2) | (u >> 1);    // rotated
        const int orow = ((rp & 3) << 7) | (w * 8 + kl); // gate*128 + k
        const float sc = ((rp & 3) == 2) ? L2 : L1;    // g gate: 2*log2e
        const float* rowp = W_hh + (size_t)p * Gdim * Hdim + (size_t)orow * Hdim;
        #pragma unroll
        for (int ks = 0; ks < 8; ++ks) {
            int k0 = ks * 16 + hi * 8;
            float4 va = *(const float4*)(rowp + k0);
            float4 vb = *(const float4*)(rowp + k0 + 4);
            H8 u8;
            u8.h[0] = (_Float16)(sc * va.x); u8.h[1] = (_Float16)(sc * va.y);
            u8.h[2] = (_Float16)(sc * va.z); u8.h[3] = (_Float16)(sc * va.w);
            u8.h[4] = (_Float16)(sc * vb.x); u8.h[5] = (_Float16)(sc * vb.y);
            u8.h[6] = (_Float16)(sc * vb.z); u8.h[7] = (_Float16)(sc * vb.w);
            afr[ks] = u8.v;
        }
        H8 u9;
        #pragma unroll
        for (int j = 0; j < 8; ++j) u9.s[j] = 0;
        if (hi == 0) {
            u9.h[0] = (_Float16)(sc * W_ih[(size_t)p * Gdim + orow]);
            u9.h[1] = (_Float16)(sc * (b_ih[(size_t)p * Gdim + orow] +
                                       b_hh[(size_t)p * Gdim + orow]));
        }
        afr[8] = u9.v;
    }

    // swizzled ds_read_b128: row l31, chunk c = 2ks+hi
    auto ldh = [&](const unsigned short* hb, int ks) -> H8 {
        H8 r;
        int c   = ks * 2 + hi;
        int off = (l31 << 8) + ((c ^ (l31 & 15)) << 4);   // bytes
        r.u4 = *(const uint4*)((const char*)hb + off);
        return r;
    };

    // epilogue for q-pair j: acc -> new c (in cr), returns packed 2xf16 h
    // (x-elem = k_local 4hi+2j, y-elem = 4hi+2j+1 under the rotated mapping)
    auto ep_pair = [&](const f32x16& a, int j, f32x2* cr) -> unsigned {
        f32x2 yi = {a[8 * j + 0], a[8 * j + 4]};
        f32x2 yf = {a[8 * j + 1], a[8 * j + 5]};
        f32x2 yg = {a[8 * j + 2], a[8 * j + 6]};   // prescaled by 2*log2e
        f32x2 yo = {a[8 * j + 3], a[8 * j + 7]};
        f32x2 Ef = {exp2_fast(-yf.x), exp2_fast(-yf.y)};
        f32x2 Ei = {exp2_fast(-yi.x), exp2_fast(-yi.y)};
        f32x2 Eg = {exp2_fast(yg.x),  exp2_fast(yg.y)};
        f32x2 t1 = Ef + 1.0f;
        f32x2 t2 = Ei + 1.0f;
        f32x2 t3 = Eg + 1.0f;
        f32x2 t4 = Eg - 1.0f;
        f32x2 den = (t1 * t2) * t3;
        f32x2 num = (cr[j] * t2) * t3 + (L2 * t4) * t1;
        float D = den.x * den.y;
        float r = __builtin_amdgcn_rcpf(D);
        f32x2 inv = {r * den.y, r * den.x};
        f32x2 cn  = num * inv;
        cn.x = __builtin_amdgcn_fmed3f(cn.x, -30.0f, 30.0f);
        cn.y = __builtin_amdgcn_fmed3f(cn.y, -30.0f, 30.0f);
        cr[j] = cn;
        f32x2 Eo = {exp2_fast(-yo.x), exp2_fast(-yo.y)};
        f32x2 Ec = {exp2_fast(cn.x),  exp2_fast(cn.y)};
        f32x2 d2 = (Eo + 1.0f) * (Ec + 1.0f);
        float D2 = d2.x * d2.y;
        float r2 = __builtin_amdgcn_rcpf(D2);
        f32x2 j2 = {r2 * d2.y, r2 * d2.x};
        f32x2 hv = (Ec - 1.0f) * j2;
        HS ha; ha.h = (_Float16)hv.x;
        HS hc; hc.h = (_Float16)hv.y;
        return (unsigned)ha.s | ((unsigned)hc.s << 16);
    };

    // one ds_write_b64: lane's 4 contiguous h shorts, k = w*8 + 4*hi + [0..4)
    // chunk = w -> swizzled pos = w ^ (l31&15); 8-byte aligned.
    auto ep_write = [&](unsigned lo, unsigned hi2, unsigned short* wb) {
        int base = (l31 << 7) + ((w ^ (l31 & 15)) << 3) + (hi << 2);  // shorts
        uint2 v; v.x = lo; v.y = hi2;
        *(uint2*)(wb + base) = v;
    };

    // one fragment of a step: gemm of one stream (rb -> acc) interleaved with
    // the epilogue of the other stream (ar -> wb). doGemm/doEp compile-time.
    auto phase = [&](const unsigned short* rb, unsigned short* wb,
                     f32x16& acc, const f32x16& ar, f32x2* cr, float xv,
                     bool doGemm, bool doEp) {
        if (doGemm) {
            f32x16 z;
            #pragma unroll
            for (int j = 0; j < 16; ++j) z[j] = 0.f;
            // gx K-step FIRST: no LDS dependency -> MFMA pipe starts while
            // the ds_reads are still in flight.
            H8 bg;
            #pragma unroll
            for (int j = 0; j < 8; ++j) bg.s[j] = 0;
            if (hi == 0) { bg.h[0] = (_Float16)xv; bg.h[1] = (_Float16)1.0f; }
            acc = __builtin_amdgcn_mfma_f32_32x32x16_f16(afr[8], bg.v, z, 0, 0, 0);
            H8 f0 = ldh(rb, 0), f1 = ldh(rb, 1);
            H8 f2 = ldh(rb, 2), f3 = ldh(rb, 3);
            acc = __builtin_amdgcn_mfma_f32_32x32x16_f16(afr[0], f0.v, acc, 0, 0, 0);
            acc = __builtin_amdgcn_mfma_f32_32x32x16_f16(afr[1], f1.v, acc, 0, 0, 0);
            unsigned e0 = 0;
            if (doEp) e0 = ep_pair(ar, 0, cr);
            H8 f4 = ldh(rb, 4), f5 = ldh(rb, 5);
            acc = __builtin_amdgcn_mfma_f32_32x32x16_f16(afr[2], f2.v, acc, 0, 0, 0);
            acc = __builtin_amdgcn_mfma_f32_32x32x16_f16(afr[3], f3.v, acc, 0, 0, 0);
            if (doEp) { unsigned e1 = ep_pair(ar, 1, cr); ep_write(e0, e1, wb); }
            H8 f6 = ldh(rb, 6), f7 = ldh(rb, 7);
            acc = __builtin_amdgcn_mfma_f32_32x32x16_f16(afr[4], f4.v, acc, 0, 0, 0);
            acc = __builtin_amdgcn_mfma_f32_32x32x16_f16(afr[5], f5.v, acc, 0, 0, 0);
            acc = __builtin_amdgcn_mfma_f32_32x32x16_f16(afr[6], f6.v, acc, 0, 0, 0);
            acc = __builtin_amdgcn_mfma_f32_32x32x16_f16(afr[7], f7.v, acc, 0, 0, 0);
        } else if (doEp) {
            unsigned e0 = ep_pair(ar, 0, cr);
            unsigned e1 = ep_pair(ar, 1, cr);
            ep_write(e0, e1, wb);
        }
    };

    f32x2 cre0[2] = {f32x2{0.f, 0.f}, f32x2{0.f, 0.f}};
    f32x2 cre1[2] = {f32x2{0.f, 0.f}, f32x2{0.f, 0.f}};
    f32x16 acc0, acc1;
    #pragma unroll
    for (int j = 0; j < 16; ++j) { acc0[j] = 0.f; acc1[j] = 0.f; }

    const float* xp0 = x + (size_t)((0 * BH + l31) * Tdim) * Pdim + p;
    const float* xp1 = x + (size_t)((1 * BH + l31) * Tdim) * Pdim + p;
    float xv0 = xp0[0];
    float xv1 = xp1[0];

    __syncthreads();

    // one region per step, ONE barrier per step.
    // region t: all reads from buffer P, all writes to buffer P^1.
    for (int t = 0; t < Tdim; ++t) {
        const int P  = t & 1;
        const int tn = (t + 1 < Tdim) ? (t + 1) : t;
        float xn0 = xp0[(size_t)tn * Pdim];   // prefetch x(t+1)
        float xn1 = xp1[(size_t)tn * Pdim];

        // gemm_s0(t): hb0[P] -> acc0 (no ep interleave)
        phase(hb0[P], hb0[P ^ 1], acc0, acc1, cre1, xv0, true, false);
        // gemm_s1(t) || ep_s0(t): hb1[P] -> acc1 ; acc0 -> hb0[P^1]
        phase(hb1[P], hb0[P ^ 1], acc1, acc0, cre0, xv1, true, true);
        // ep_s1(t): acc1 -> hb1[P^1]
        phase(hb1[P], hb1[P ^ 1], acc1, acc1, cre1, 0.f, false, true);

        __syncthreads();
        xv0 = xn0;
        xv1 = xn1;
    }
    // final h (t=95 writes buffer 0): stream0 in hb0[0], stream1 in hb1[0]

    // ---- FC: out[b][o][p] = sum_k W_fc[p][o][k]*h[b][k] + b_fc[p][o] ----
    const float* wfc = W_fc + (size_t)p * Odim * Hdim;
    const float* bfc = b_fc + (size_t)p * Odim;
    for (int i = tid; i < Bdim * Odim; i += 1024) {
        int o = i % Odim;
        int b = i / Odim;            // global batch 0..63
        int bl = (b < BH) ? b : (b - BH);
        const unsigned short* hr = (b < BH) ? (hb0[0] + (bl << 7))
                                            : (hb1[0] + (bl << 7));
        float s = bfc[o];
        const float* wr = wfc + o * Hdim;
        #pragma unroll 8
        for (int k2 = 0; k2 < Hdim; ++k2) {
            int idx = (((k2 >> 3) ^ (bl & 15)) << 3) + (k2 & 7);   // unswizzle
            HS s2; s2.s = hr[idx];
            s = __builtin_fmaf(wr[k2], (float)s2.h, s);
        }
        out[(size_t)b * Odim * Pdim + (size_t)o * Pdim + p] = s;
    }
}

extern "C" void kernel_launch(void* const* d_in, const int* in_sizes, int n_in,
                              void* d_out, int out_size, void* d_ws, size_t ws_size,
                              hipStream_t stream) {
    const float* x    = (const float*)d_in[0];
    const float* W_ih = (const float*)d_in[1];
    const float* W_hh = (const float*)d_in[2];
    const float* b_ih = (const float*)d_in[3];
    const float* b_hh = (const float*)d_in[4];
    const float* W_fc = (const float*)d_in[5];
    const float* b_fc = (const float*)d_in[6];
    float* out = (float*)d_out;

    lstm_fused<<<dim3(Pdim), dim3(1024), 0, stream>>>(x, W_ih, W_hh, b_ih, b_hh, W_fc, b_fc, out);
}

// Round 9
// 385.526 us; speedup vs baseline: 1.7443x; 1.0123x over previous
//
#include <hip/hip_runtime.h>
#include <hip/hip_bf16.h>

#define Bdim 64
#define Tdim 96
#define Pdim 256
#define Hdim 128
#define Gdim 512   // 4*H
#define Odim 24
#define BH   32    // batches per stream (two streams per block)

typedef _Float16 f16x8 __attribute__((ext_vector_type(8)));
typedef float    f32x16 __attribute__((ext_vector_type(16)));
typedef float    f32x2  __attribute__((ext_vector_type(2)));

union H8 { uint4 u4; unsigned short s[8]; _Float16 h[8]; f16x8 v; };
union HS { _Float16 h; unsigned short s; };

__device__ __forceinline__ float exp2_fast(float x) {
#if __has_builtin(__builtin_amdgcn_exp2f)
    return __builtin_amdgcn_exp2f(x);
#else
    return __expf(x * 0.6931471805599453f);
#endif
}

// R6 (3rd resubmit; 2x GPU-acquisition timeout + 1x container failure):
// schedule restructure. R5 counters: conflicts fixed (1.9e7->3.1e6) but time
// unchanged at 330us rocprof; VALUBusy 55% / MFMA-pipe ~7% per SIMD / ~40%
// issue idle. Cause: 3-phase step [g0][g1||ep0][ep1] leaves one pipe empty
// 2/3 of the time under barrier lockstep. Fix: fuse per step into [g0 || g1
// as two interleaved dep-dist-2 MFMA chains] then [ep0 ; ep1] (4 independent
// exp-chains/lane). Same instruction count, same 1 barrier/step, same math.
// Gates: VGPR<=128 combined (16-wave/CU hard budget, R3/R4), FETCH ~60 MB.
//
// h storage: row b = 256 B = 16 chunks of 16 B, chunk c at position c ^ (b&15)
// (XOR swizzle). Gemm read of chunk c = 2ks+hi by lane b=l31 is ONE aligned
// ds_read_b128 at byte offset 256*l31 + 16*(c^(l31&15)) -> balanced banks.
// Rotated k-map (R5): kl = rot(u) makes each lane's 4 h outputs contiguous ->
// epilogue writes are ONE ds_write_b64 per wave per stream (conflict-fixed).
//
// Math (verified R2-R5, absmax 9.77e-4): log2e-prescaled weights (2log2e for
// g), gx fused as 9th MFMA K-step, scaled-domain cell state, paired-rcp
// epilogue (6 trans per (b,k)).
__global__ __launch_bounds__(1024, 4)
void lstm_fused(const float* __restrict__ x,
                const float* __restrict__ W_ih,
                const float* __restrict__ W_hh,
                const float* __restrict__ b_ih,
                const float* __restrict__ b_hh,
                const float* __restrict__ W_fc,
                const float* __restrict__ b_fc,
                float* __restrict__ out)
{
    __shared__ alignas(16) unsigned short hb0[2][BH * Hdim];  // stream0 h, dbuf, swizzled
    __shared__ alignas(16) unsigned short hb1[2][BH * Hdim];  // stream1 h, dbuf, swizzled

    const int p   = blockIdx.x;
    const int tid = threadIdx.x;
    const int w   = tid >> 6;    // wave 0..15
    const int l31 = tid & 31;
    const int hi  = (tid >> 5) & 1;

    const float L1 = 1.4426950408889634f;  // log2(e)
    const float L2 = 2.0f * L1;

    for (int i = tid; i < 2 * BH * Hdim; i += 1024) ((unsigned short*)hb0)[i] = 0;
    for (int i = tid; i < 2 * BH * Hdim; i += 1024) ((unsigned short*)hb1)[i] = 0;

    // ---- preload shared A fragments (time-invariant): W_hh rows + gx row ----
    // Rotated row map (R5): gate = r&3, k_local = rot(u)=((u&1)<<2)|(u>>1) so a
    // lane's 4 epilogue outputs are contiguous shorts; chunk invariant kept.
    f16x8 afr[9];
    {
        const int rp   = w * 32 + l31;                 // block row id
        const int u    = l31 >> 2;                     // 3-bit within-chunk idx
        const int kl   = ((u & 1) << 2) | (u >> 1);    // rotated
        const int orow = ((rp & 3) << 7) | (w * 8 + kl); // gate*128 + k
        const float sc = ((rp & 3) == 2) ? L2 : L1;    // g gate: 2*log2e
        const float* rowp = W_hh + (size_t)p * Gdim * Hdim + (size_t)orow * Hdim;
        #pragma unroll
        for (int ks = 0; ks < 8; ++ks) {
            int k0 = ks * 16 + hi * 8;
            float4 va = *(const float4*)(rowp + k0);
            float4 vb = *(const float4*)(rowp + k0 + 4);
            H8 u8;
            u8.h[0] = (_Float16)(sc * va.x); u8.h[1] = (_Float16)(sc * va.y);
            u8.h[2] = (_Float16)(sc * va.z); u8.h[3] = (_Float16)(sc * va.w);
            u8.h[4] = (_Float16)(sc * vb.x); u8.h[5] = (_Float16)(sc * vb.y);
            u8.h[6] = (_Float16)(sc * vb.z); u8.h[7] = (_Float16)(sc * vb.w);
            afr[ks] = u8.v;
        }
        H8 u9;
        #pragma unroll
        for (int j = 0; j < 8; ++j) u9.s[j] = 0;
        if (hi == 0) {
            u9.h[0] = (_Float16)(sc * W_ih[(size_t)p * Gdim + orow]);
            u9.h[1] = (_Float16)(sc * (b_ih[(size_t)p * Gdim + orow] +
                                       b_hh[(size_t)p * Gdim + orow]));
        }
        afr[8] = u9.v;
    }

    // swizzled ds_read_b128: row l31, chunk c = 2ks+hi
    auto ldh = [&](const unsigned short* hb, int ks) -> H8 {
        H8 r;
        int c   = ks * 2 + hi;
        int off = (l31 << 8) + ((c ^ (l31 & 15)) << 4);   // bytes
        r.u4 = *(const uint4*)((const char*)hb + off);
        return r;
    };

    // epilogue for q-pair j: acc -> new c (in cr), returns packed 2xf16 h
    auto ep_pair = [&](const f32x16& a, int j, f32x2* cr) -> unsigned {
        f32x2 yi = {a[8 * j + 0], a[8 * j + 4]};
        f32x2 yf = {a[8 * j + 1], a[8 * j + 5]};
        f32x2 yg = {a[8 * j + 2], a[8 * j + 6]};   // prescaled by 2*log2e
        f32x2 yo = {a[8 * j + 3], a[8 * j + 7]};
        f32x2 Ef = {exp2_fast(-yf.x), exp2_fast(-yf.y)};
        f32x2 Ei = {exp2_fast(-yi.x), exp2_fast(-yi.y)};
        f32x2 Eg = {exp2_fast(yg.x),  exp2_fast(yg.y)};
        f32x2 t1 = Ef + 1.0f;
        f32x2 t2 = Ei + 1.0f;
        f32x2 t3 = Eg + 1.0f;
        f32x2 t4 = Eg - 1.0f;
        f32x2 den = (t1 * t2) * t3;
        f32x2 num = (cr[j] * t2) * t3 + (L2 * t4) * t1;
        float D = den.x * den.y;
        float r = __builtin_amdgcn_rcpf(D);
        f32x2 inv = {r * den.y, r * den.x};
        f32x2 cn  = num * inv;
        cn.x = __builtin_amdgcn_fmed3f(cn.x, -30.0f, 30.0f);
        cn.y = __builtin_amdgcn_fmed3f(cn.y, -30.0f, 30.0f);
        cr[j] = cn;
        f32x2 Eo = {exp2_fast(-yo.x), exp2_fast(-yo.y)};
        f32x2 Ec = {exp2_fast(cn.x),  exp2_fast(cn.y)};
        f32x2 d2 = (Eo + 1.0f) * (Ec + 1.0f);
        float D2 = d2.x * d2.y;
        float r2 = __builtin_amdgcn_rcpf(D2);
        f32x2 j2 = {r2 * d2.y, r2 * d2.x};
        f32x2 hv = (Ec - 1.0f) * j2;
        HS ha; ha.h = (_Float16)hv.x;
        HS hc; hc.h = (_Float16)hv.y;
        return (unsigned)ha.s | ((unsigned)hc.s << 16);
    };

    // one ds_write_b64: lane's 4 contiguous h shorts, k = w*8 + 4*hi + [0..4)
    auto ep_write = [&](unsigned lo, unsigned hi2, unsigned short* wb) {
        int base = (l31 << 7) + ((w ^ (l31 & 15)) << 3) + (hi << 2);  // shorts
        uint2 v; v.x = lo; v.y = hi2;
        *(uint2*)(wb + base) = v;
    };

    f32x2 cre0[2] = {f32x2{0.f, 0.f}, f32x2{0.f, 0.f}};
    f32x2 cre1[2] = {f32x2{0.f, 0.f}, f32x2{0.f, 0.f}};

    const float* xp0 = x + (size_t)((0 * BH + l31) * Tdim) * Pdim + p;
    const float* xp1 = x + (size_t)((1 * BH + l31) * Tdim) * Pdim + p;
    float xv0 = xp0[0];
    float xv1 = xp1[0];

    __syncthreads();

    // one region per step, ONE barrier per step. Region t: all LDS reads from
    // buffer P, all writes to buffer P^1. Section 1: both gemms, interleaved
    // (independent MFMA chains). Section 2: both epilogues (independent
    // VALU/trans chains).
    for (int t = 0; t < Tdim; ++t) {
        const int P  = t & 1;
        const unsigned short* rb0 = hb0[P];
        const unsigned short* rb1 = hb1[P];
        unsigned short* wbuf0 = hb0[P ^ 1];
        unsigned short* wbuf1 = hb1[P ^ 1];
        const int tn = (t + 1 < Tdim) ? (t + 1) : t;
        float xn0 = xp0[(size_t)tn * Pdim];   // prefetch x(t+1)
        float xn1 = xp1[(size_t)tn * Pdim];

        // ---- section 1: fused gemm, two interleaved 9-MFMA chains ----
        f32x16 acc0, acc1;
        {
            f32x16 z;
            #pragma unroll
            for (int j = 0; j < 16; ++j) z[j] = 0.f;
            // gx K-steps first: no LDS dependency, MFMA pipe starts immediately
            H8 bg0, bg1;
            #pragma unroll
            for (int j = 0; j < 8; ++j) { bg0.s[j] = 0; bg1.s[j] = 0; }
            if (hi == 0) {
                HS b0x; b0x.h = (_Float16)xv0;
                HS b1x; b1x.h = (_Float16)xv1;
                bg0.u4.x = (unsigned)b0x.s | (0x3C00u << 16);
                bg1.u4.x = (unsigned)b1x.s | (0x3C00u << 16);
            }
            acc0 = __builtin_amdgcn_mfma_f32_32x32x16_f16(afr[8], bg0.v, z, 0, 0, 0);
            acc1 = __builtin_amdgcn_mfma_f32_32x32x16_f16(afr[8], bg1.v, z, 0, 0, 0);
            H8 a0 = ldh(rb0, 0), b0 = ldh(rb1, 0);
            H8 a1 = ldh(rb0, 1), b1 = ldh(rb1, 1);
            acc0 = __builtin_amdgcn_mfma_f32_32x32x16_f16(afr[0], a0.v, acc0, 0, 0, 0);
            acc1 = __builtin_amdgcn_mfma_f32_32x32x16_f16(afr[0], b0.v, acc1, 0, 0, 0);
            H8 a2 = ldh(rb0, 2), b2 = ldh(rb1, 2);
            acc0 = __builtin_amdgcn_mfma_f32_32x32x16_f16(afr[1], a1.v, acc0, 0, 0, 0);
            acc1 = __builtin_amdgcn_mfma_f32_32x32x16_f16(afr[1], b1.v, acc1, 0, 0, 0);
            H8 a3 = ldh(rb0, 3), b3 = ldh(rb1, 3);
            acc0 = __builtin_amdgcn_mfma_f32_32x32x16_f16(afr[2], a2.v, acc0, 0, 0, 0);
            acc1 = __builtin_amdgcn_mfma_f32_32x32x16_f16(afr[2], b2.v, acc1, 0, 0, 0);
            H8 a4 = ldh(rb0, 4), b4 = ldh(rb1, 4);
            acc0 = __builtin_amdgcn_mfma_f32_32x32x16_f16(afr[3], a3.v, acc0, 0, 0, 0);
            acc1 = __builtin_amdgcn_mfma_f32_32x32x16_f16(afr[3], b3.v, acc1, 0, 0, 0);
            H8 a5 = ldh(rb0, 5), b5 = ldh(rb1, 5);
            acc0 = __builtin_amdgcn_mfma_f32_32x32x16_f16(afr[4], a4.v, acc0, 0, 0, 0);
            acc1 = __builtin_amdgcn_mfma_f32_32x32x16_f16(afr[4], b4.v, acc1, 0, 0, 0);
            H8 a6 = ldh(rb0, 6), b6 = ldh(rb1, 6);
            acc0 = __builtin_amdgcn_mfma_f32_32x32x16_f16(afr[5], a5.v, acc0, 0, 0, 0);
            acc1 = __builtin_amdgcn_mfma_f32_32x32x16_f16(afr[5], b5.v, acc1, 0, 0, 0);
            H8 a7 = ldh(rb0, 7), b7 = ldh(rb1, 7);
            acc0 = __builtin_amdgcn_mfma_f32_32x32x16_f16(afr[6], a6.v, acc0, 0, 0, 0);
            acc1 = __builtin_amdgcn_mfma_f32_32x32x16_f16(afr[6], b6.v, acc1, 0, 0, 0);
            acc0 = __builtin_amdgcn_mfma_f32_32x32x16_f16(afr[7], a7.v, acc0, 0, 0, 0);
            acc1 = __builtin_amdgcn_mfma_f32_32x32x16_f16(afr[7], b7.v, acc1, 0, 0, 0);
        }

        // ---- section 2: both epilogues (4 independent exp-chains per lane) ----
        {
            unsigned e00 = ep_pair(acc0, 0, cre0);
            unsigned e01 = ep_pair(acc0, 1, cre0);
            ep_write(e00, e01, wbuf0);
            unsigned e10 = ep_pair(acc1, 0, cre1);
            unsigned e11 = ep_pair(acc1, 1, cre1);
            ep_write(e10, e11, wbuf1);
        }

        __syncthreads();
        xv0 = xn0;
        xv1 = xn1;
    }
    // final h (t=95 writes buffer 0): stream0 in hb0[0], stream1 in hb1[0]

    // ---- FC: out[b][o][p] = sum_k W_fc[p][o][k]*h[b][k] + b_fc[p][o] ----
    const float* wfc = W_fc + (size_t)p * Odim * Hdim;
    const float* bfc = b_fc + (size_t)p * Odim;
    for (int i = tid; i < Bdim * Odim; i += 1024) {
        int o = i % Odim;
        int b = i / Odim;            // global batch 0..63
        int bl = (b < BH) ? b : (b - BH);
        const unsigned short* hr = (b < BH) ? (hb0[0] + (bl << 7))
                                            : (hb1[0] + (bl << 7));
        float s = bfc[o];
        const float* wr = wfc + o * Hdim;
        #pragma unroll 8
        for (int k2 = 0; k2 < Hdim; ++k2) {
            int idx = (((k2 >> 3) ^ (bl & 15)) << 3) + (k2 & 7);   // unswizzle
            HS s2; s2.s = hr[idx];
            s = __builtin_fmaf(wr[k2], (float)s2.h, s);
        }
        out[(size_t)b * Odim * Pdim + (size_t)o * Pdim + p] = s;
    }
}

extern "C" void kernel_launch(void* const* d_in, const int* in_sizes, int n_in,
                              void* d_out, int out_size, void* d_ws, size_t ws_size,
                              hipStream_t stream) {
    const float* x    = (const float*)d_in[0];
    const float* W_ih = (const float*)d_in[1];
    const float* W_hh = (const float*)d_in[2];
    const float* b_ih = (const float*)d_in[3];
    const float* b_hh = (const float*)d_in[4];
    const float* W_fc = (const float*)d_in[5];
    const float* b_fc = (const float*)d_in[6];
    float* out = (float*)d_out;

    lstm_fused<<<dim3(Pdim), dim3(1024), 0, stream>>>(x, W_ih, W_hh, b_ih, b_hh, W_fc, b_fc, out);
}